// Round 3
// baseline (91.687 us; speedup 1.0000x reference)
//
#include <hip/hip_runtime.h>
#include <cstdint>

#define H_ 128
#define V_ 2048
#define F_ 512
#define B_ 2
#define FOCAL_ 3.0f
#define ZNEAR_ 0.01f
#define EPS_ 1e-8f
#define PAD_ 1e-3f

// ---------------- kernel A: project verts + per-face precompute (fused) ----
// One block, 1024 threads: phase 1 projects all B*V verts into LDS,
// phase 2 computes one face record per thread (B*F == 1024 exactly).
// face record (16 floats): [x1,y1,x2,y2 | z0,z1,z2,denom | dx21,dy21,dx02,dy02 | x0,y0,aok,pad]
__global__ __launch_bounds__(1024) void k_prep(const float* __restrict__ vw,
                                               const int* __restrict__ faces,
                                               const float* __restrict__ R,
                                               const float* __restrict__ T,
                                               float* __restrict__ fd,
                                               float4* __restrict__ bb) {
  __shared__ float ndc[B_ * V_ * 3];  // 48 KB
  int t = threadIdx.x;

  // ---- phase 1: projection (exact reference op order; __f*_rn blocks FMA) ----
  for (int tid = t; tid < B_ * V_; tid += 1024) {
    int b = tid >> 11;  // V_ = 2048
    const float* v  = vw + tid * 3;
    const float* Rb = R + b * 9;
    const float* Tb = T + b * 3;
    float vx = v[0], vy = v[1], vz = v[2];
    float o[3];
#pragma unroll
    for (int k = 0; k < 3; ++k) {
      // einsum 'bvj,bjk->bvk': sum_j verts[j]*R[j,k], then + T[k]
      float a = __fadd_rn(__fadd_rn(__fmul_rn(vx, Rb[k]), __fmul_rn(vy, Rb[3 + k])),
                          __fmul_rn(vz, Rb[6 + k]));
      o[k] = __fadd_rn(a, Tb[k]);
    }
    float z = o[2];
    ndc[tid * 3 + 0] = __fdiv_rn(__fmul_rn(FOCAL_, o[0]), z);
    ndc[tid * 3 + 1] = __fdiv_rn(__fmul_rn(FOCAL_, o[1]), z);
    ndc[tid * 3 + 2] = z;
  }
  __syncthreads();

  // ---- phase 2: face records (tid == t, B_*F_ == 1024) ----
  {
    int tid = t;
    int b = tid >> 9;            // F_ = 512
    int f = tid & (F_ - 1);
    int i0 = faces[f * 3 + 0], i1 = faces[f * 3 + 1], i2 = faces[f * 3 + 2];
    const float* nb = ndc + b * V_ * 3;
    float x0 = nb[i0 * 3], y0 = nb[i0 * 3 + 1], z0 = nb[i0 * 3 + 2];
    float x1 = nb[i1 * 3], y1 = nb[i1 * 3 + 1], z1 = nb[i1 * 3 + 2];
    float x2 = nb[i2 * 3], y2 = nb[i2 * 3 + 1], z2 = nb[i2 * 3 + 2];
    float area = __fsub_rn(__fmul_rn(__fsub_rn(x1, x0), __fsub_rn(y2, y0)),
                           __fmul_rn(__fsub_rn(y1, y0), __fsub_rn(x2, x0)));
    bool ok = fabsf(area) > EPS_;
    float denom = ok ? area : EPS_;
    float* o = fd + tid * 16;
    o[0]  = x1;  o[1]  = y1;  o[2]  = x2;  o[3]  = y2;
    o[4]  = z0;  o[5]  = z1;  o[6]  = z2;  o[7]  = denom;
    o[8]  = __fsub_rn(x2, x1);  o[9]  = __fsub_rn(y2, y1);
    o[10] = __fsub_rn(x0, x2);  o[11] = __fsub_rn(y0, y2);
    o[12] = x0;  o[13] = y0;  o[14] = ok ? 1.0f : 0.0f;  o[15] = 0.0f;
    float4 box;
    if (ok) {  // invalid faces can never win the argmin -> empty bbox culls them
      box.x = fminf(fminf(x0, x1), x2) - PAD_;
      box.y = fmaxf(fmaxf(x0, x1), x2) + PAD_;
      box.z = fminf(fminf(y0, y1), y2) - PAD_;
      box.w = fmaxf(fmaxf(y0, y1), y2) + PAD_;
    } else {
      box.x = 1e30f; box.y = -1e30f; box.z = 1e30f; box.w = -1e30f;
    }
    bb[tid] = box;
  }
}

// exact-order replica of reference _seg_d2 (no FMA contraction)
__device__ __forceinline__ float seg_d2(float px, float py, float ax, float ay,
                                        float bx, float by) {
  float abx = __fsub_rn(bx, ax), aby = __fsub_rn(by, ay);
  float apx = __fsub_rn(px, ax), apy = __fsub_rn(py, ay);
  float num = __fadd_rn(__fmul_rn(apx, abx), __fmul_rn(apy, aby));
  float den = __fadd_rn(__fadd_rn(__fmul_rn(abx, abx), __fmul_rn(aby, aby)), EPS_);
  float t = __fdiv_rn(num, den);
  t = fminf(fmaxf(t, 0.0f), 1.0f);
  float dx = __fsub_rn(apx, __fmul_rn(t, abx));
  float dy = __fsub_rn(apy, __fmul_rn(t, aby));
  return __fadd_rn(__fmul_rn(dx, dx), __fmul_rn(dy, dy));
}

// ---------------- kernel B: rasterize ----------------
// 512 blocks: b(1b) | iy(7b) | half(1b). 512 threads: 8 waves x 64 lanes.
// lane = pixel within half-row; wave q scans faces [q*64, q*64+64).
__global__ __launch_bounds__(512) void k_raster(const float* __restrict__ fd,
                                                const float4* __restrict__ bb,
                                                float* __restrict__ out) {
  __shared__ float lf[F_ * 16];                 // 32 KB
  __shared__ float4 lbb[F_];                    // 8 KB
  __shared__ unsigned long long red[64 * 8];    // 4 KB
  int blk = blockIdx.x;
  int b  = blk >> 8;
  int iy = (blk >> 1) & (H_ - 1);
  int h  = blk & 1;
  int t = threadIdx.x;
  int lane = t & 63;
  int q = t >> 6;
  int ix = h * 64 + lane;

  // stage face data + bboxes into LDS (coalesced float4)
  const float4* src = (const float4*)(fd + b * F_ * 16);
  float4* dst = (float4*)lf;
  for (int i = t; i < F_ * 4; i += 512) dst[i] = src[i];
  for (int i = t; i < F_; i += 512) lbb[i] = bb[b * F_ + i];
  __syncthreads();

  // 1 - (2i+1)/128 is exact in fp32 -> bit-identical to reference's s grid
  float px = 1.0f - (float)(2 * ix + 1) * 0.0078125f;
  float py = 1.0f - (float)(2 * iy + 1) * 0.0078125f;
  const float INF = __int_as_float(0x7f800000);
  float best = INF;
  int bidx = q * 64;

#pragma unroll 2
  for (int f = q * 64; f < q * 64 + 64; ++f) {
    float4 box = lbb[f];
    bool cull = (px < box.x) || (px > box.y) || (py < box.z) || (py > box.w);
    if (__all(cull)) continue;  // wave-uniform skip (conservative bbox)
    const float* Fp = &lf[f * 16];
    float x1 = Fp[0], y1 = Fp[1], x2 = Fp[2], y2 = Fp[3];
    float z0 = Fp[4], z1 = Fp[5], z2 = Fp[6], denom = Fp[7];
    float dx21 = Fp[8], dy21 = Fp[9], dx02 = Fp[10], dy02 = Fp[11];
    float aok = Fp[14];
    float w0 = __fdiv_rn(__fsub_rn(__fmul_rn(dx21, __fsub_rn(py, y1)),
                                   __fmul_rn(dy21, __fsub_rn(px, x1))), denom);
    float w1 = __fdiv_rn(__fsub_rn(__fmul_rn(dx02, __fsub_rn(py, y2)),
                                   __fmul_rn(dy02, __fsub_rn(px, x2))), denom);
    float w2 = __fsub_rn(__fsub_rn(1.0f, w0), w1);
    float zp = __fadd_rn(__fadd_rn(__fmul_rn(w0, z0), __fmul_rn(w1, z1)),
                         __fmul_rn(w2, z2));
    bool valid = (w0 >= 0.0f) && (w1 >= 0.0f) && (w2 >= 0.0f) &&
                 (zp > ZNEAR_) && (aok > 0.5f);
    float zs = valid ? zp : INF;
    if (zs < best) { best = zs; bidx = f; }  // strict < == first-argmin
  }

  // cross-wave reduce: packed (z_bits, idx) -> lexicographic min == argmin-first
  red[lane * 8 + q] =
      ((unsigned long long)__float_as_uint(best) << 32) | (unsigned long long)(unsigned)bidx;
  __syncthreads();

  if (q == 0) {
    unsigned long long m = red[lane * 8];
#pragma unroll
    for (int j = 1; j < 8; ++j) {
      unsigned long long v = red[lane * 8 + j];
      m = (v < m) ? v : m;
    }
    unsigned zb = (unsigned)(m >> 32);
    int idx = (int)(m & 0xffffffffu);
    bool hit = zb < 0x7f800000u;  // isfinite(min zsort)

    // recompute winner attributes (exact reference op order)
    const float* Fp = &lf[idx * 16];
    float x1 = Fp[0], y1 = Fp[1], x2 = Fp[2], y2 = Fp[3];
    float z0 = Fp[4], z1 = Fp[5], z2 = Fp[6], denom = Fp[7];
    float dx21 = Fp[8], dy21 = Fp[9], dx02 = Fp[10], dy02 = Fp[11];
    float x0 = Fp[12], y0 = Fp[13];
    float w0 = __fdiv_rn(__fsub_rn(__fmul_rn(dx21, __fsub_rn(py, y1)),
                                   __fmul_rn(dy21, __fsub_rn(px, x1))), denom);
    float w1 = __fdiv_rn(__fsub_rn(__fmul_rn(dx02, __fsub_rn(py, y2)),
                                   __fmul_rn(dy02, __fsub_rn(px, x2))), denom);
    float w2 = __fsub_rn(__fsub_rn(1.0f, w0), w1);
    float zp = __fadd_rn(__fadd_rn(__fmul_rn(w0, z0), __fmul_rn(w1, z1)),
                         __fmul_rn(w2, z2));
    float d01 = seg_d2(px, py, x0, y0, x1, y1);
    float d12 = seg_d2(px, py, x1, y1, x2, y2);
    float d20 = seg_d2(px, py, x2, y2, x0, y0);
    float d2 = fminf(d01, fminf(d12, d20));  // winner passed inside -> dists = -d2

    int pix = ((b * H_ + iy) * H_) + ix;
    // outputs concatenated flat in return order (promoted to fp32):
    // pix_to_face [0,32768) | zbuf [32768,65536) | bary [65536,163840) | dists [163840,196608)
    out[pix]                 = hit ? (float)idx : -1.0f;
    out[32768 + pix]         = hit ? zp : -1.0f;
    out[65536 + pix * 3 + 0] = hit ? w0 : -1.0f;
    out[65536 + pix * 3 + 1] = hit ? w1 : -1.0f;
    out[65536 + pix * 3 + 2] = hit ? w2 : -1.0f;
    out[163840 + pix]        = hit ? -d2 : -1.0f;
  }
}

extern "C" void kernel_launch(void* const* d_in, const int* in_sizes, int n_in,
                              void* d_out, int out_size, void* d_ws, size_t ws_size,
                              hipStream_t stream) {
  const float* vw    = (const float*)d_in[0];
  const int*   faces = (const int*)d_in[1];
  const float* R     = (const float*)d_in[2];
  const float* T     = (const float*)d_in[3];
  float* out = (float*)d_out;
  float* ws  = (float*)d_ws;
  // ws layout (floats): face records [0,16384) | bboxes [16384,20480)
  float*  fd  = ws;
  float4* bbp = (float4*)(ws + 16384);
  k_prep<<<1, 1024, 0, stream>>>(vw, faces, R, T, fd, bbp);
  k_raster<<<512, 512, 0, stream>>>(fd, bbp, out);
}

// Round 4
// 84.430 us; speedup vs baseline: 1.0860x; 1.0860x over previous
//
#include <hip/hip_runtime.h>
#include <cstdint>

#define H_ 128
#define V_ 2048
#define F_ 512
#define B_ 2
#define FOCAL_ 3.0f
#define ZNEAR_ 0.01f
#define EPS_ 1e-8f
#define PAD_ 1e-3f

// ---------------- kernel A: project verts + per-face precompute (fused) ----
// One block, 1024 threads: phase 1 projects all B*V verts into LDS,
// phase 2 computes one face record per thread (B*F == 1024 exactly).
// face record (4 float4): q0=[x1,y1,x2,y2] q1=[z0,z1,z2,denom]
//                         q2=[dx21,dy21,dx02,dy02] q3=[x0,y0,aok,pad]
__global__ __launch_bounds__(1024) void k_prep(const float* __restrict__ vw,
                                               const int* __restrict__ faces,
                                               const float* __restrict__ R,
                                               const float* __restrict__ T,
                                               float* __restrict__ fd,
                                               float4* __restrict__ bb) {
  __shared__ float ndc[B_ * V_ * 3];  // 48 KB
  int t = threadIdx.x;

  // ---- phase 1: projection (exact reference op order; __f*_rn blocks FMA) ----
  for (int tid = t; tid < B_ * V_; tid += 1024) {
    int b = tid >> 11;  // V_ = 2048
    const float* v  = vw + tid * 3;
    const float* Rb = R + b * 9;
    const float* Tb = T + b * 3;
    float vx = v[0], vy = v[1], vz = v[2];
    float o[3];
#pragma unroll
    for (int k = 0; k < 3; ++k) {
      // einsum 'bvj,bjk->bvk': sum_j verts[j]*R[j,k], then + T[k]
      float a = __fadd_rn(__fadd_rn(__fmul_rn(vx, Rb[k]), __fmul_rn(vy, Rb[3 + k])),
                          __fmul_rn(vz, Rb[6 + k]));
      o[k] = __fadd_rn(a, Tb[k]);
    }
    float z = o[2];
    ndc[tid * 3 + 0] = __fdiv_rn(__fmul_rn(FOCAL_, o[0]), z);
    ndc[tid * 3 + 1] = __fdiv_rn(__fmul_rn(FOCAL_, o[1]), z);
    ndc[tid * 3 + 2] = z;
  }
  __syncthreads();

  // ---- phase 2: face records (tid == t, B_*F_ == 1024) ----
  {
    int tid = t;
    int b = tid >> 9;            // F_ = 512
    int f = tid & (F_ - 1);
    int i0 = faces[f * 3 + 0], i1 = faces[f * 3 + 1], i2 = faces[f * 3 + 2];
    const float* nb = ndc + b * V_ * 3;
    float x0 = nb[i0 * 3], y0 = nb[i0 * 3 + 1], z0 = nb[i0 * 3 + 2];
    float x1 = nb[i1 * 3], y1 = nb[i1 * 3 + 1], z1 = nb[i1 * 3 + 2];
    float x2 = nb[i2 * 3], y2 = nb[i2 * 3 + 1], z2 = nb[i2 * 3 + 2];
    float area = __fsub_rn(__fmul_rn(__fsub_rn(x1, x0), __fsub_rn(y2, y0)),
                           __fmul_rn(__fsub_rn(y1, y0), __fsub_rn(x2, x0)));
    bool ok = fabsf(area) > EPS_;
    float denom = ok ? area : EPS_;
    float* o = fd + tid * 16;
    o[0]  = x1;  o[1]  = y1;  o[2]  = x2;  o[3]  = y2;
    o[4]  = z0;  o[5]  = z1;  o[6]  = z2;  o[7]  = denom;
    o[8]  = __fsub_rn(x2, x1);  o[9]  = __fsub_rn(y2, y1);
    o[10] = __fsub_rn(x0, x2);  o[11] = __fsub_rn(y0, y2);
    o[12] = x0;  o[13] = y0;  o[14] = ok ? 1.0f : 0.0f;  o[15] = 0.0f;
    float4 box;
    if (ok) {  // invalid faces get empty bbox -> never enter any wave's mask
      box.x = fminf(fminf(x0, x1), x2) - PAD_;
      box.y = fmaxf(fmaxf(x0, x1), x2) + PAD_;
      box.z = fminf(fminf(y0, y1), y2) - PAD_;
      box.w = fmaxf(fmaxf(y0, y1), y2) + PAD_;
    } else {
      box.x = 1e30f; box.y = -1e30f; box.z = 1e30f; box.w = -1e30f;
    }
    bb[tid] = box;
  }
}

// exact-order replica of reference _seg_d2 (no FMA contraction)
__device__ __forceinline__ float seg_d2(float px, float py, float ax, float ay,
                                        float bx, float by) {
  float abx = __fsub_rn(bx, ax), aby = __fsub_rn(by, ay);
  float apx = __fsub_rn(px, ax), apy = __fsub_rn(py, ay);
  float num = __fadd_rn(__fmul_rn(apx, abx), __fmul_rn(apy, aby));
  float den = __fadd_rn(__fadd_rn(__fmul_rn(abx, abx), __fmul_rn(aby, aby)), EPS_);
  float t = __fdiv_rn(num, den);
  t = fminf(fmaxf(t, 0.0f), 1.0f);
  float dx = __fsub_rn(apx, __fmul_rn(t, abx));
  float dy = __fsub_rn(apy, __fmul_rn(t, aby));
  return __fadd_rn(__fmul_rn(dx, dx), __fmul_rn(dy, dy));
}

// ---------------- kernel B: rasterize ----------------
// 512 blocks: b(1b) | iy(7b) | half(1b). 512 threads: 8 waves x 64 lanes.
// lane = pixel within half-row; wave q owns faces [q*64, q*64+64).
// Per wave: ballot bbox mask once, then iterate set bits only (ctz).
__global__ __launch_bounds__(512) void k_raster(const float* __restrict__ fd,
                                                const float4* __restrict__ bb,
                                                float* __restrict__ out) {
  __shared__ float4 lf4[F_ * 4];                // 32 KB face records
  __shared__ unsigned long long red[64 * 8];    // 4 KB reduction
  const float* lf = (const float*)lf4;
  int blk = blockIdx.x;
  int b  = blk >> 8;
  int iy = (blk >> 1) & (H_ - 1);
  int h  = blk & 1;
  int t = threadIdx.x;
  int lane = t & 63;
  int q = t >> 6;
  int ix = h * 64 + lane;

  // stage face records into LDS (coalesced float4)
  const float4* src = (const float4*)(fd + b * F_ * 16);
  for (int i = t; i < F_ * 4; i += 512) lf4[i] = src[i];
  __syncthreads();

  // 1 - (2i+1)/128 is exact in fp32 -> bit-identical to reference's s grid
  float px = 1.0f - (float)(2 * ix + 1) * 0.0078125f;
  float py = 1.0f - (float)(2 * iy + 1) * 0.0078125f;
  // wave pixel-x range: px decreases with ix; lanes are contiguous
  float pxmax = 1.0f - (float)(2 * (h * 64) + 1) * 0.0078125f;
  float pxmin = 1.0f - (float)(2 * (h * 64 + 63) + 1) * 0.0078125f;

  // build survival mask: lane l tests face q*64+l bbox vs this wave's strip
  float4 box = bb[b * F_ + q * 64 + lane];
  bool ov = (box.x <= pxmax) && (box.y >= pxmin) && (box.z <= py) && (box.w >= py);
  unsigned long long m = __ballot(ov);  // wave-uniform

  const float INF = __int_as_float(0x7f800000);
  float best = INF;
  int bidx = q * 64;

  while (m) {
    int f = q * 64 + __builtin_ctzll(m);
    m &= m - 1;
    float4 q0 = lf4[f * 4 + 0];  // x1,y1,x2,y2
    float4 q1 = lf4[f * 4 + 1];  // z0,z1,z2,denom
    float4 q2 = lf4[f * 4 + 2];  // dx21,dy21,dx02,dy02
    // exact reference numerators (same op order as w0/w1 before the divide)
    float e0 = __fsub_rn(__fmul_rn(q2.x, __fsub_rn(py, q0.y)),
                         __fmul_rn(q2.y, __fsub_rn(px, q0.x)));
    float e1 = __fsub_rn(__fmul_rn(q2.z, __fsub_rn(py, q0.w)),
                         __fmul_rn(q2.w, __fsub_rn(px, q0.z)));
    // sign(e/denom) is exact without dividing (IEEE sign rule; +-0 >= 0 both ways)
    bool dpos = q1.w > 0.0f;
    bool s0 = dpos ? (e0 >= 0.0f) : (e0 <= 0.0f);  // == (w0 >= 0)
    bool s1 = dpos ? (e1 >= 0.0f) : (e1 <= 0.0f);  // == (w1 >= 0)
    if (__any(s0 && s1)) {
      float w0 = __fdiv_rn(e0, q1.w);
      float w1 = __fdiv_rn(e1, q1.w);
      float w2 = __fsub_rn(__fsub_rn(1.0f, w0), w1);
      float zp = __fadd_rn(__fadd_rn(__fmul_rn(w0, q1.x), __fmul_rn(w1, q1.y)),
                           __fmul_rn(w2, q1.z));
      bool valid = s0 && s1 && (w2 >= 0.0f) && (zp > ZNEAR_);
      float zs = valid ? zp : INF;
      if (zs < best) { best = zs; bidx = f; }  // strict < == first-argmin
    }
  }

  // cross-wave reduce: packed (z_bits, idx) -> lexicographic min == argmin-first
  red[lane * 8 + q] =
      ((unsigned long long)__float_as_uint(best) << 32) | (unsigned long long)(unsigned)bidx;
  __syncthreads();

  if (q == 0) {
    unsigned long long mm = red[lane * 8];
#pragma unroll
    for (int j = 1; j < 8; ++j) {
      unsigned long long v = red[lane * 8 + j];
      mm = (v < mm) ? v : mm;
    }
    unsigned zb = (unsigned)(mm >> 32);
    int idx = (int)(mm & 0xffffffffu);
    bool hit = zb < 0x7f800000u;  // isfinite(min zsort)

    // recompute winner attributes (exact reference op order)
    const float* Fp = &lf[idx * 16];
    float x1 = Fp[0], y1 = Fp[1], x2 = Fp[2], y2 = Fp[3];
    float z0 = Fp[4], z1 = Fp[5], z2 = Fp[6], denom = Fp[7];
    float dx21 = Fp[8], dy21 = Fp[9], dx02 = Fp[10], dy02 = Fp[11];
    float x0 = Fp[12], y0 = Fp[13];
    float w0 = __fdiv_rn(__fsub_rn(__fmul_rn(dx21, __fsub_rn(py, y1)),
                                   __fmul_rn(dy21, __fsub_rn(px, x1))), denom);
    float w1 = __fdiv_rn(__fsub_rn(__fmul_rn(dx02, __fsub_rn(py, y2)),
                                   __fmul_rn(dy02, __fsub_rn(px, x2))), denom);
    float w2 = __fsub_rn(__fsub_rn(1.0f, w0), w1);
    float zp = __fadd_rn(__fadd_rn(__fmul_rn(w0, z0), __fmul_rn(w1, z1)),
                         __fmul_rn(w2, z2));
    float d01 = seg_d2(px, py, x0, y0, x1, y1);
    float d12 = seg_d2(px, py, x1, y1, x2, y2);
    float d20 = seg_d2(px, py, x2, y2, x0, y0);
    float d2 = fminf(d01, fminf(d12, d20));  // winner passed inside -> dists = -d2

    int pix = ((b * H_ + iy) * H_) + ix;
    // outputs concatenated flat in return order (promoted to fp32):
    // pix_to_face [0,32768) | zbuf [32768,65536) | bary [65536,163840) | dists [163840,196608)
    out[pix]                 = hit ? (float)idx : -1.0f;
    out[32768 + pix]         = hit ? zp : -1.0f;
    out[65536 + pix * 3 + 0] = hit ? w0 : -1.0f;
    out[65536 + pix * 3 + 1] = hit ? w1 : -1.0f;
    out[65536 + pix * 3 + 2] = hit ? w2 : -1.0f;
    out[163840 + pix]        = hit ? -d2 : -1.0f;
  }
}

extern "C" void kernel_launch(void* const* d_in, const int* in_sizes, int n_in,
                              void* d_out, int out_size, void* d_ws, size_t ws_size,
                              hipStream_t stream) {
  const float* vw    = (const float*)d_in[0];
  const int*   faces = (const int*)d_in[1];
  const float* R     = (const float*)d_in[2];
  const float* T     = (const float*)d_in[3];
  float* out = (float*)d_out;
  float* ws  = (float*)d_ws;
  // ws layout (floats): face records [0,16384) | bboxes [16384,20480)
  float*  fd  = ws;
  float4* bbp = (float4*)(ws + 16384);
  k_prep<<<1, 1024, 0, stream>>>(vw, faces, R, T, fd, bbp);
  k_raster<<<512, 512, 0, stream>>>(fd, bbp, out);
}

// Round 5
// 81.390 us; speedup vs baseline: 1.1265x; 1.0373x over previous
//
#include <hip/hip_runtime.h>
#include <cstdint>

#define H_ 128
#define V_ 2048
#define F_ 512
#define B_ 2
#define FOCAL_ 3.0f
#define ZNEAR_ 0.01f
#define EPS_ 1e-8f
#define PAD_ 1e-3f

// exact-order replica of reference _seg_d2 (no FMA contraction)
__device__ __forceinline__ float seg_d2(float px, float py, float ax, float ay,
                                        float bx, float by) {
  float abx = __fsub_rn(bx, ax), aby = __fsub_rn(by, ay);
  float apx = __fsub_rn(px, ax), apy = __fsub_rn(py, ay);
  float num = __fadd_rn(__fmul_rn(apx, abx), __fmul_rn(apy, aby));
  float den = __fadd_rn(__fadd_rn(__fmul_rn(abx, abx), __fmul_rn(aby, aby)), EPS_);
  float t = __fdiv_rn(num, den);
  t = fminf(fmaxf(t, 0.0f), 1.0f);
  float dx = __fsub_rn(apx, __fmul_rn(t, abx));
  float dy = __fsub_rn(apy, __fmul_rn(t, aby));
  return __fadd_rn(__fmul_rn(dx, dx), __fmul_rn(dy, dy));
}

// ---------------- single fused kernel ----------------
// 512 blocks: b(1b) | iy(7b) | half(1b). 512 threads: 8 waves x 64 lanes.
// Each block redundantly projects its batch's 2048 verts (51K VALU ops,
// trivial) and builds all 512 face records in LDS -- kills the separate
// prep kernel, its launch latency, and the fd/bb global round-trip.
// face record (4 float4): q0=[x1,y1,x2,y2] q1=[z0,z1,z2,denom]
//                         q2=[dx21,dy21,dx02,dy02] q3=[x0,y0,aok,pad]
__global__ __launch_bounds__(512) void k_all(const float* __restrict__ vw,
                                             const int* __restrict__ faces,
                                             const float* __restrict__ R,
                                             const float* __restrict__ T,
                                             float* __restrict__ out) {
  __shared__ float ndc[V_ * 3];                 // 24 KB (own batch only)
  __shared__ float4 lf4[F_ * 4];                // 32 KB face records
  __shared__ float4 lbb[F_];                    // 8 KB bboxes
  __shared__ unsigned long long red[64 * 8];    // 4 KB reduction
  const float* lf = (const float*)lf4;
  int blk = blockIdx.x;
  int b  = blk >> 8;
  int iy = (blk >> 1) & (H_ - 1);
  int h  = blk & 1;
  int t = threadIdx.x;
  int lane = t & 63;
  int q = t >> 6;
  int ix = h * 64 + lane;

  // ---- phase 1: project this batch's verts (exact reference op order) ----
  {
    const float* Rb = R + b * 9;
    const float* Tb = T + b * 3;
    float r00 = Rb[0], r01 = Rb[1], r02 = Rb[2];
    float r10 = Rb[3], r11 = Rb[4], r12 = Rb[5];
    float r20 = Rb[6], r21 = Rb[7], r22 = Rb[8];
    float t0 = Tb[0], t1 = Tb[1], t2 = Tb[2];
    for (int i = t; i < V_; i += 512) {
      const float* v = vw + (b * V_ + i) * 3;
      float vx = v[0], vy = v[1], vz = v[2];
      // einsum 'bvj,bjk->bvk' + T; __f*_rn blocks FMA contraction
      float ox = __fadd_rn(__fadd_rn(__fadd_rn(__fmul_rn(vx, r00), __fmul_rn(vy, r10)),
                                     __fmul_rn(vz, r20)), t0);
      float oy = __fadd_rn(__fadd_rn(__fadd_rn(__fmul_rn(vx, r01), __fmul_rn(vy, r11)),
                                     __fmul_rn(vz, r21)), t1);
      float oz = __fadd_rn(__fadd_rn(__fadd_rn(__fmul_rn(vx, r02), __fmul_rn(vy, r12)),
                                     __fmul_rn(vz, r22)), t2);
      ndc[i * 3 + 0] = __fdiv_rn(__fmul_rn(FOCAL_, ox), oz);
      ndc[i * 3 + 1] = __fdiv_rn(__fmul_rn(FOCAL_, oy), oz);
      ndc[i * 3 + 2] = oz;
    }
  }
  __syncthreads();

  // ---- phase 2: face records, one per thread (F_ == blockDim) ----
  {
    int f = t;
    int i0 = faces[f * 3 + 0], i1 = faces[f * 3 + 1], i2 = faces[f * 3 + 2];
    float x0 = ndc[i0 * 3], y0 = ndc[i0 * 3 + 1], z0 = ndc[i0 * 3 + 2];
    float x1 = ndc[i1 * 3], y1 = ndc[i1 * 3 + 1], z1 = ndc[i1 * 3 + 2];
    float x2 = ndc[i2 * 3], y2 = ndc[i2 * 3 + 1], z2 = ndc[i2 * 3 + 2];
    float area = __fsub_rn(__fmul_rn(__fsub_rn(x1, x0), __fsub_rn(y2, y0)),
                           __fmul_rn(__fsub_rn(y1, y0), __fsub_rn(x2, x0)));
    bool ok = fabsf(area) > EPS_;
    float denom = ok ? area : EPS_;
    lf4[f * 4 + 0] = make_float4(x1, y1, x2, y2);
    lf4[f * 4 + 1] = make_float4(z0, z1, z2, denom);
    lf4[f * 4 + 2] = make_float4(__fsub_rn(x2, x1), __fsub_rn(y2, y1),
                                 __fsub_rn(x0, x2), __fsub_rn(y0, y2));
    lf4[f * 4 + 3] = make_float4(x0, y0, ok ? 1.0f : 0.0f, 0.0f);
    float4 box;
    if (ok) {  // invalid faces get empty bbox -> never enter any wave's mask
      box.x = fminf(fminf(x0, x1), x2) - PAD_;
      box.y = fmaxf(fmaxf(x0, x1), x2) + PAD_;
      box.z = fminf(fminf(y0, y1), y2) - PAD_;
      box.w = fmaxf(fmaxf(y0, y1), y2) + PAD_;
    } else {
      box.x = 1e30f; box.y = -1e30f; box.z = 1e30f; box.w = -1e30f;
    }
    lbb[f] = box;
  }
  __syncthreads();

  // ---- phase 3: rasterize; wave q owns faces [q*64, q*64+64) ----
  // 1 - (2i+1)/128 is exact in fp32 -> bit-identical to reference's s grid
  float px = 1.0f - (float)(2 * ix + 1) * 0.0078125f;
  float py = 1.0f - (float)(2 * iy + 1) * 0.0078125f;
  float pxmax = 1.0f - (float)(2 * (h * 64) + 1) * 0.0078125f;
  float pxmin = 1.0f - (float)(2 * (h * 64 + 63) + 1) * 0.0078125f;

  // survival mask: lane l tests face q*64+l bbox vs this wave's pixel strip
  float4 box = lbb[q * 64 + lane];
  bool ov = (box.x <= pxmax) && (box.y >= pxmin) && (box.z <= py) && (box.w >= py);
  unsigned long long m = __ballot(ov);  // wave-uniform

  const float INF = __int_as_float(0x7f800000);
  float best = INF;
  int bidx = q * 64;

  while (m) {
    int f = q * 64 + __builtin_ctzll(m);
    m &= m - 1;
    float4 q0 = lf4[f * 4 + 0];  // x1,y1,x2,y2
    float4 q1 = lf4[f * 4 + 1];  // z0,z1,z2,denom
    float4 q2 = lf4[f * 4 + 2];  // dx21,dy21,dx02,dy02
    // exact reference numerators (same op order as w0/w1 before the divide)
    float e0 = __fsub_rn(__fmul_rn(q2.x, __fsub_rn(py, q0.y)),
                         __fmul_rn(q2.y, __fsub_rn(px, q0.x)));
    float e1 = __fsub_rn(__fmul_rn(q2.z, __fsub_rn(py, q0.w)),
                         __fmul_rn(q2.w, __fsub_rn(px, q0.z)));
    // sign(e/denom) is exact without dividing (IEEE sign rule; +-0 >= 0 both ways)
    bool dpos = q1.w > 0.0f;
    bool s0 = dpos ? (e0 >= 0.0f) : (e0 <= 0.0f);  // == (w0 >= 0)
    bool s1 = dpos ? (e1 >= 0.0f) : (e1 <= 0.0f);  // == (w1 >= 0)
    if (__any(s0 && s1)) {
      float w0 = __fdiv_rn(e0, q1.w);
      float w1 = __fdiv_rn(e1, q1.w);
      float w2 = __fsub_rn(__fsub_rn(1.0f, w0), w1);
      float zp = __fadd_rn(__fadd_rn(__fmul_rn(w0, q1.x), __fmul_rn(w1, q1.y)),
                           __fmul_rn(w2, q1.z));
      bool valid = s0 && s1 && (w2 >= 0.0f) && (zp > ZNEAR_);
      float zs = valid ? zp : INF;
      if (zs < best) { best = zs; bidx = f; }  // strict < == first-argmin
    }
  }

  // cross-wave reduce: packed (z_bits, idx) -> lexicographic min == argmin-first
  red[lane * 8 + q] =
      ((unsigned long long)__float_as_uint(best) << 32) | (unsigned long long)(unsigned)bidx;
  __syncthreads();

  if (q == 0) {
    unsigned long long mm = red[lane * 8];
#pragma unroll
    for (int j = 1; j < 8; ++j) {
      unsigned long long v = red[lane * 8 + j];
      mm = (v < mm) ? v : mm;
    }
    unsigned zb = (unsigned)(mm >> 32);
    int idx = (int)(mm & 0xffffffffu);
    bool hit = zb < 0x7f800000u;  // isfinite(min zsort)

    // recompute winner attributes (exact reference op order)
    const float* Fp = &lf[idx * 16];
    float x1 = Fp[0], y1 = Fp[1], x2 = Fp[2], y2 = Fp[3];
    float z0 = Fp[4], z1 = Fp[5], z2 = Fp[6], denom = Fp[7];
    float dx21 = Fp[8], dy21 = Fp[9], dx02 = Fp[10], dy02 = Fp[11];
    float x0 = Fp[12], y0 = Fp[13];
    float w0 = __fdiv_rn(__fsub_rn(__fmul_rn(dx21, __fsub_rn(py, y1)),
                                   __fmul_rn(dy21, __fsub_rn(px, x1))), denom);
    float w1 = __fdiv_rn(__fsub_rn(__fmul_rn(dx02, __fsub_rn(py, y2)),
                                   __fmul_rn(dy02, __fsub_rn(px, x2))), denom);
    float w2 = __fsub_rn(__fsub_rn(1.0f, w0), w1);
    float zp = __fadd_rn(__fadd_rn(__fmul_rn(w0, z0), __fmul_rn(w1, z1)),
                         __fmul_rn(w2, z2));
    float d01 = seg_d2(px, py, x0, y0, x1, y1);
    float d12 = seg_d2(px, py, x1, y1, x2, y2);
    float d20 = seg_d2(px, py, x2, y2, x0, y0);
    float d2 = fminf(d01, fminf(d12, d20));  // winner passed inside -> dists = -d2

    int pix = ((b * H_ + iy) * H_) + ix;
    // outputs concatenated flat in return order (promoted to fp32):
    // pix_to_face [0,32768) | zbuf [32768,65536) | bary [65536,163840) | dists [163840,196608)
    out[pix]                 = hit ? (float)idx : -1.0f;
    out[32768 + pix]         = hit ? zp : -1.0f;
    out[65536 + pix * 3 + 0] = hit ? w0 : -1.0f;
    out[65536 + pix * 3 + 1] = hit ? w1 : -1.0f;
    out[65536 + pix * 3 + 2] = hit ? w2 : -1.0f;
    out[163840 + pix]        = hit ? -d2 : -1.0f;
  }
}

extern "C" void kernel_launch(void* const* d_in, const int* in_sizes, int n_in,
                              void* d_out, int out_size, void* d_ws, size_t ws_size,
                              hipStream_t stream) {
  const float* vw    = (const float*)d_in[0];
  const int*   faces = (const int*)d_in[1];
  const float* R     = (const float*)d_in[2];
  const float* T     = (const float*)d_in[3];
  float* out = (float*)d_out;
  (void)d_ws; (void)ws_size;  // no workspace needed -- everything lives in LDS
  k_all<<<512, 512, 0, stream>>>(vw, faces, R, T, out);
}